// Round 15
// baseline (935.652 us; speedup 1.0000x reference)
//
#include <hip/hip_runtime.h>

// Child-Sum Tree-LSTM, level-synchronous, B=8 L=8192 D=768.
// Per level: 5 fused K=768 GEMM products + LSTM cell epilogue.
//   acc0..2 (i,o,u) = hs @ (0.5*W_iou + U_iou)^T
//   acc3 (fl-pre)   = hl@Wfp^T + hr@Wfh^T,  Wfp = 0.5*W_f + U_f, Wfh = 0.5*W_f
//   acc4 (fr-pre)   = hl@Wfh^T + hr@Wfp^T
// R15 tiering:
//  M>=4096: kernel A (R4/R6) — 128x64, 4 waves, 2 blocks/CU, vmcnt(9).  [357us L0]
//  M==2048: tree_small (R7) — 128x32, 3 blocks/CU, vmcnt(7), BK=32.
//  M<=1024: tree_tiny — 128x32, BK=64 (12 kts instead of 24: halves the
//    serial barrier/latency chain; grids <=192 blocks so 1 block/CU is free).
// Dead ends measured: deeper pipelines, phase splits, direct-to-reg A or B,
// 6-group algebra, cooperative/persistent tail fusion.

typedef _Float16 half8 __attribute__((ext_vector_type(8)));
typedef float f32x4 __attribute__((ext_vector_type(4)));

#define ROWB 1536        // bytes per 768-elem fp16 row
#define NT 24            // 768 / 32
#define BUFA 36864       // kernel A buffer: A 16384 + B 20480
#define BUFT 26624       // tree_small buffer: A 16384 + B 10240
#define BUFY 53248       // tree_tiny buffer: A 32768 + B 20480

__device__ __forceinline__ float sigm(float x){ return 1.f/(1.f+__expf(-x)); }
__device__ __forceinline__ float tanhfast(float x){ return 1.f - 2.f/(1.f+__expf(2.f*x)); }

__device__ __forceinline__ void gload16(const void* g, void* l){
  __builtin_amdgcn_global_load_lds((const __attribute__((address_space(1))) void*)g,
                                   (__attribute__((address_space(3))) void*)l, 16, 0, 0);
}

// Bw: 5 mats of 768x768 fp16: [0..2]=0.5*W_iou+U_iou (i,o,u), [3]=Wfp=0.5Wf+Uf, [4]=Wfh=0.5Wf
__global__ void prep_weights(const float* __restrict__ Wiou, const float* __restrict__ Uiou,
                             const float* __restrict__ Wf, const float* __restrict__ Uf,
                             _Float16* __restrict__ Bw)
{
    const int n1 = 2304 * 768, n2 = n1 + 589824, n3 = n2 + 589824;
    int stride = gridDim.x * blockDim.x;
    for (int idx = blockIdx.x * blockDim.x + threadIdx.x; idx < n3; idx += stride) {
        float v;
        if (idx < n1)      v = __fmaf_rn(0.5f, Wiou[idx], Uiou[idx]);
        else if (idx < n2) { int k = idx - n1; v = __fmaf_rn(0.5f, Wf[k], Uf[k]); }
        else               { int k = idx - n2; v = 0.5f * Wf[k]; }
        Bw[idx] = (_Float16)v;
    }
}

__global__ void cast_leaves(const float* __restrict__ x, _Float16* __restrict__ h, int n8)
{
    int stride = gridDim.x * blockDim.x;
    for (int i = blockIdx.x * blockDim.x + threadIdx.x; i < n8; i += stride) {
        float4 v0 = ((const float4*)x)[2 * i];
        float4 v1 = ((const float4*)x)[2 * i + 1];
        half8 o = { (_Float16)v0.x, (_Float16)v0.y, (_Float16)v0.z, (_Float16)v0.w,
                    (_Float16)v1.x, (_Float16)v1.y, (_Float16)v1.z, (_Float16)v1.w };
        ((half8*)h)[i] = o;
    }
}

// ================= kernel A: big levels (M>=4096) — unchanged =================
__global__ __launch_bounds__(256, 2) void tree_level(
    const _Float16* __restrict__ Hc, const float* __restrict__ Cc,
    const _Float16* __restrict__ Bw,
    const float* __restrict__ biou, const float* __restrict__ bfv,
    _Float16* __restrict__ Hn, float* __restrict__ Cn,
    int M, int mblocks, int firstLevel)
{
    __shared__ __align__(16) char smem[2 * BUFA];
    const int tid = threadIdx.x;
    const int lane = tid & 63;
    const int w = tid >> 6;
    const int wm = w >> 1;
    const int wd = w & 1;

    const int nwg = mblocks * 12;
    const int orig = blockIdx.x;
    const int xcd = orig & 7, qx = nwg >> 3, rx = nwg & 7;
    const int v = (xcd < rx ? xcd * (qx + 1) : rx * (qx + 1) + (xcd - rx) * qx) + (orig >> 3);
    const int mb = v / 12;
    const int d0c = v - mb * 12;
    const int mBase = mb * 128;
    const int d0 = d0c * 64;

    const int l3 = lane >> 3, j = lane & 7;
    const int jjA = j ^ l3;
    const int rbase = w * 8 + l3;
    unsigned offH[4];
#pragma unroll
    for (int s = 0; s < 4; ++s) {
        int gr = mBase + s * 32 + rbase;
        if (gr >= M) gr = M - 1;
        offH[s] = (unsigned)(2 * gr + (jjA >> 2)) * ROWB + (jjA & 3) * 16;
    }
    const int pB = w * 8 + l3;
    unsigned offWb[5];
#pragma unroll
    for (int t = 0; t < 5; ++t)
        offWb[t] = (unsigned)(t * 768 + d0 + 2 * pB + (jjA >> 2)) * ROWB + (jjA & 3) * 16;
    const int wK = w * 1024;

#define STAGE_A(bi, ko) do { \
    _Pragma("unroll") for (int s = 0; s < 4; ++s) \
        gload16((const char*)Hc + offH[s] + (ko), smem + (bi) * BUFA + s * 4096 + wK); \
    _Pragma("unroll") for (int t = 0; t < 5; ++t) \
        gload16((const char*)Bw + offWb[t] + (ko), smem + (bi) * BUFA + 16384 + t * 4096 + wK); \
} while (0)

    const int q = lane >> 4;
    const int lr16 = lane & 15;
    int offA[4], offB[2];
#pragma unroll
    for (int fm = 0; fm < 4; ++fm) {
        int r = wm * 64 + fm * 16 + lr16;
        offA[fm] = r * 128 + ((q ^ (r & 7)) * 16);
    }
#pragma unroll
    for (int fd = 0; fd < 2; ++fd) {
        int cl = wd * 32 + fd * 16 + lr16;
        int p = cl >> 1;
        int jb = ((cl & 1) * 4 + q) ^ (p & 7);
        offB[fd] = 16384 + p * 128 + jb * 16;
    }

    f32x4 acc[5][4][2];
#pragma unroll
    for (int g = 0; g < 5; ++g)
#pragma unroll
        for (int a = 0; a < 4; ++a)
#pragma unroll
            for (int b2 = 0; b2 < 2; ++b2)
                acc[g][a][b2] = (f32x4){0.f, 0.f, 0.f, 0.f};

    STAGE_A(0, 0);
    int cur = 0;
    for (int kt = 0; kt < NT; ++kt) {
        if (kt + 1 < NT) {
            STAGE_A(cur ^ 1, (kt + 1) * 64);
            asm volatile("s_waitcnt vmcnt(9)" ::: "memory");
        } else {
            asm volatile("s_waitcnt vmcnt(0)" ::: "memory");
        }
        __builtin_amdgcn_s_barrier();
        __builtin_amdgcn_sched_barrier(0);
        const char* bb = smem + cur * BUFA;
        half8 hl[4], hr[4];
#pragma unroll
        for (int fm = 0; fm < 4; ++fm) {
            hl[fm] = *(const half8*)(bb + offA[fm]);
            hr[fm] = *(const half8*)(bb + (offA[fm] ^ 64));
        }
        __builtin_amdgcn_s_setprio(1);
#pragma unroll
        for (int fd = 0; fd < 2; ++fd) {
            const char* bp = bb + offB[fd];
            half8 b0 = *(const half8*)(bp);
            half8 b1 = *(const half8*)(bp + 4096);
            half8 b2 = *(const half8*)(bp + 8192);
            half8 b3 = *(const half8*)(bp + 12288);   // Wfp
            half8 b4 = *(const half8*)(bp + 16384);   // Wfh
#pragma unroll
            for (int fm = 0; fm < 4; ++fm) {
                half8 hs = hl[fm] + hr[fm];
                acc[0][fm][fd] = __builtin_amdgcn_mfma_f32_16x16x32_f16(hs, b0, acc[0][fm][fd], 0, 0, 0);
                acc[1][fm][fd] = __builtin_amdgcn_mfma_f32_16x16x32_f16(hs, b1, acc[1][fm][fd], 0, 0, 0);
                acc[2][fm][fd] = __builtin_amdgcn_mfma_f32_16x16x32_f16(hs, b2, acc[2][fm][fd], 0, 0, 0);
                acc[3][fm][fd] = __builtin_amdgcn_mfma_f32_16x16x32_f16(hl[fm], b3, acc[3][fm][fd], 0, 0, 0);
                acc[3][fm][fd] = __builtin_amdgcn_mfma_f32_16x16x32_f16(hr[fm], b4, acc[3][fm][fd], 0, 0, 0);
                acc[4][fm][fd] = __builtin_amdgcn_mfma_f32_16x16x32_f16(hl[fm], b4, acc[4][fm][fd], 0, 0, 0);
                acc[4][fm][fd] = __builtin_amdgcn_mfma_f32_16x16x32_f16(hr[fm], b3, acc[4][fm][fd], 0, 0, 0);
            }
        }
        __builtin_amdgcn_s_setprio(0);
        if (kt + 1 < NT) __builtin_amdgcn_s_barrier();
        cur ^= 1;
    }

#pragma unroll
    for (int fd = 0; fd < 2; ++fd) {
        const int col = d0 + wd * 32 + fd * 16 + lr16;
        const float bi = biou[col];
        const float bo = biou[768 + col];
        const float bu = biou[1536 + col];
        const float bf = bfv[col];
#pragma unroll
        for (int fm = 0; fm < 4; ++fm) {
            const int rb = mBase + wm * 64 + fm * 16 + q * 4;
#pragma unroll
            for (int r4 = 0; r4 < 4; ++r4) {
                int row = rb + r4;
                if (row < M) {
                    float iv = acc[0][fm][fd][r4] + bi;
                    float ov = acc[1][fm][fd][r4] + bo;
                    float uv = acc[2][fm][fd][r4] + bu;
                    float fl = sigm(acc[3][fm][fd][r4] + bf);
                    float fr = sigm(acc[4][fm][fd][r4] + bf);
                    float clv = 0.f, crv = 0.f;
                    if (!firstLevel) {
                        clv = Cc[(size_t)(2 * row) * 768 + col];
                        crv = Cc[(size_t)(2 * row + 1) * 768 + col];
                    }
                    float c = sigm(iv) * tanhfast(uv) + fl * clv + fr * crv;
                    float h = sigm(ov) * tanhfast(c);
                    Hn[(size_t)row * 768 + col] = (_Float16)h;
                    Cn[(size_t)row * 768 + col] = c;
                }
            }
        }
    }
}

// ================= tree_small: M=2048 — unchanged (R7) =================
__global__ __launch_bounds__(256, 3) void tree_small(
    const _Float16* __restrict__ Hc, const float* __restrict__ Cc,
    const _Float16* __restrict__ Bw,
    const float* __restrict__ biou, const float* __restrict__ bfv,
    _Float16* __restrict__ Hn, float* __restrict__ Cn,
    int M)
{
    __shared__ __align__(16) char smem[2 * BUFT];
    const int tid = threadIdx.x;
    const int lane = tid & 63;
    const int w = tid >> 6;
    const int wm = w >> 1;
    const int wd = w & 1;
    const int bid = blockIdx.x;
    const int mb = bid / 24;
    const int d0c = bid - mb * 24;
    const int mBase = mb * 128;
    const int d0 = d0c * 32;

    const int l3 = lane >> 3, j = lane & 7;
    const int jj0 = j ^ l3;

    unsigned offHa[4];
    int dstA[4];
#pragma unroll
    for (int s = 0; s < 4; ++s) {
        int u = s * 4 + w;
        int gr = mBase + u * 8 + l3;
        if (gr >= M) gr = M - 1;
        offHa[s] = (unsigned)(2 * gr + (jj0 >> 2)) * ROWB + (jj0 & 3) * 16;
        dstA[s] = u * 1024;
    }
    unsigned offWb[3];
    int dstB[3];
#pragma unroll
    for (int s = 0; s < 3; ++s) {
        int i = s * 4 + w;
        if (i >= 10) i -= 2;
        int t = i >> 1, half = i & 1;
        int p = half * 8 + l3;
        offWb[s] = (unsigned)(t * 768 + d0 + 2 * p + (jj0 >> 2)) * ROWB + (jj0 & 3) * 16;
        dstB[s] = 16384 + t * 2048 + half * 1024;
    }

#define STAGE_T(bi_, ko) do { \
    _Pragma("unroll") for (int s = 0; s < 4; ++s) \
        gload16((const char*)Hc + offHa[s] + (ko), smem + (bi_) * BUFT + dstA[s]); \
    _Pragma("unroll") for (int s = 0; s < 3; ++s) \
        gload16((const char*)Bw + offWb[s] + (ko), smem + (bi_) * BUFT + dstB[s]); \
} while (0)

    const int q = lane >> 4;
    const int lr16 = lane & 15;
    int offA[4];
#pragma unroll
    for (int fm = 0; fm < 4; ++fm) {
        int r = wm * 64 + fm * 16 + lr16;
        offA[fm] = r * 128 + ((q ^ (r & 7)) * 16);
    }
    int offB;
    {
        int cl = wd * 16 + lr16;
        int p = cl >> 1;
        int jb = ((cl & 1) * 4 + q) ^ (p & 7);
        offB = 16384 + p * 128 + jb * 16;
    }

    f32x4 acc[5][4];
#pragma unroll
    for (int g = 0; g < 5; ++g)
#pragma unroll
        for (int a = 0; a < 4; ++a)
            acc[g][a] = (f32x4){0.f, 0.f, 0.f, 0.f};

    STAGE_T(0, 0);
    int cur = 0;
    for (int kt = 0; kt < NT; ++kt) {
        if (kt + 1 < NT) {
            STAGE_T(cur ^ 1, (kt + 1) * 64);
            asm volatile("s_waitcnt vmcnt(7)" ::: "memory");
        } else {
            asm volatile("s_waitcnt vmcnt(0)" ::: "memory");
        }
        __builtin_amdgcn_s_barrier();
        __builtin_amdgcn_sched_barrier(0);
        const char* bb = smem + cur * BUFT;
        half8 b0 = *(const half8*)(bb + offB);
        half8 b1 = *(const half8*)(bb + offB + 2048);
        half8 b2 = *(const half8*)(bb + offB + 4096);
        half8 b3 = *(const half8*)(bb + offB + 6144);   // Wfp
        half8 b4 = *(const half8*)(bb + offB + 8192);   // Wfh
        __builtin_amdgcn_s_setprio(1);
#pragma unroll
        for (int fm = 0; fm < 4; ++fm) {
            half8 hl = *(const half8*)(bb + offA[fm]);
            half8 hr = *(const half8*)(bb + (offA[fm] ^ 64));
            acc[3][fm] = __builtin_amdgcn_mfma_f32_16x16x32_f16(hl, b3, acc[3][fm], 0, 0, 0);
            acc[4][fm] = __builtin_amdgcn_mfma_f32_16x16x32_f16(hl, b4, acc[4][fm], 0, 0, 0);
            half8 hs = hl + hr;
            acc[0][fm] = __builtin_amdgcn_mfma_f32_16x16x32_f16(hs, b0, acc[0][fm], 0, 0, 0);
            acc[1][fm] = __builtin_amdgcn_mfma_f32_16x16x32_f16(hs, b1, acc[1][fm], 0, 0, 0);
            acc[2][fm] = __builtin_amdgcn_mfma_f32_16x16x32_f16(hs, b2, acc[2][fm], 0, 0, 0);
            acc[3][fm] = __builtin_amdgcn_mfma_f32_16x16x32_f16(hr, b4, acc[3][fm], 0, 0, 0);
            acc[4][fm] = __builtin_amdgcn_mfma_f32_16x16x32_f16(hr, b3, acc[4][fm], 0, 0, 0);
        }
        __builtin_amdgcn_s_setprio(0);
        if (kt + 1 < NT) __builtin_amdgcn_s_barrier();
        cur ^= 1;
    }

    const int col = d0 + wd * 16 + lr16;
    const float bi = biou[col];
    const float bo = biou[768 + col];
    const float bu = biou[1536 + col];
    const float bf = bfv[col];
#pragma unroll
    for (int fm = 0; fm < 4; ++fm) {
        const int rb = mBase + wm * 64 + fm * 16 + q * 4;
#pragma unroll
        for (int r4 = 0; r4 < 4; ++r4) {
            int row = rb + r4;
            if (row < M) {
                float iv = acc[0][fm][r4] + bi;
                float ov = acc[1][fm][r4] + bo;
                float uv = acc[2][fm][r4] + bu;
                float fl = sigm(acc[3][fm][r4] + bf);
                float fr = sigm(acc[4][fm][r4] + bf);
                float clv = Cc[(size_t)(2 * row) * 768 + col];
                float crv = Cc[(size_t)(2 * row + 1) * 768 + col];
                float c = sigm(iv) * tanhfast(uv) + fl * clv + fr * crv;
                float h = sigm(ov) * tanhfast(c);
                Hn[(size_t)row * 768 + col] = (_Float16)h;
                Cn[(size_t)row * 768 + col] = c;
            }
        }
    }
}

// ================= tree_tiny: M<=1024, BK=64 (12 kts) =================
// LDS per buffer: A 128 rows x 256B (row r chunk c in [0,16): jj=c^(r&15);
//   side=jj>>3 (0=HL,1=HR), 16B-sub=jj&7 of H row 2*(mBase+r)+side).
// B at +32768: 5 mats x 32 cols x 128B (col cl chunk c in [0,8):
//   jj=c^(cl&7), 16B-sub jj of weight row d0+cl).
__global__ __launch_bounds__(256, 1) void tree_tiny(
    const _Float16* __restrict__ Hc, const float* __restrict__ Cc,
    const _Float16* __restrict__ Bw,
    const float* __restrict__ biou, const float* __restrict__ bfv,
    _Float16* __restrict__ Hn, float* __restrict__ Cn,
    float* __restrict__ out,
    int M, int finalLevel)
{
    __shared__ __align__(16) char smem[2 * BUFY];
    const int tid = threadIdx.x;
    const int lane = tid & 63;
    const int w = tid >> 6;
    const int wm = w >> 1;
    const int wd = w & 1;
    const int bid = blockIdx.x;
    const int mb = bid / 24;
    const int d0c = bid - mb * 24;
    const int mBase = mb * 128;
    const int d0 = d0c * 32;

    // A staging: 32 instr (8/wave). instr u=s*4+w: rows u*4 + (lane>>4), chunk lane&15.
    const int rA = lane >> 4;
    const int cA = lane & 15;
    unsigned offHa[8];
    int dstA[8];
#pragma unroll
    for (int s = 0; s < 8; ++s) {
        int u = s * 4 + w;
        int r = u * 4 + rA;
        int jj = cA ^ (r & 15);
        int gr = mBase + r;
        if (gr >= M) gr = M - 1;
        offHa[s] = (unsigned)(2 * gr + (jj >> 3)) * ROWB + (jj & 7) * 16;
        dstA[s] = u * 1024;
    }
    // B staging: 20 instr (5/wave). instr v=s*4+w: t=v>>2, i=v&3;
    // col=i*8+(lane>>3), chunk lane&7.
    unsigned offWb[5];
    int dstB[5];
#pragma unroll
    for (int s = 0; s < 5; ++s) {
        int vv = s * 4 + w;
        int t = vv >> 2, i = vv & 3;
        int cl = i * 8 + (lane >> 3);
        int jj = (lane & 7) ^ (cl & 7);
        offWb[s] = (unsigned)(t * 768 + d0 + cl) * ROWB + jj * 16;
        dstB[s] = 32768 + t * 4096 + i * 1024;
    }

#define STAGE_Y(bi_, ko) do { \
    _Pragma("unroll") for (int s = 0; s < 8; ++s) \
        gload16((const char*)Hc + offHa[s] + (ko), smem + (bi_) * BUFY + dstA[s]); \
    _Pragma("unroll") for (int s = 0; s < 5; ++s) \
        gload16((const char*)Bw + offWb[s] + (ko), smem + (bi_) * BUFY + dstB[s]); \
} while (0)

    // read offsets (ks=0; ks=1 is ^64, hr is ^128)
    const int q = lane >> 4;
    const int lr16 = lane & 15;
    int offA0[4];
#pragma unroll
    for (int fm = 0; fm < 4; ++fm) {
        int r = wm * 64 + fm * 16 + lr16;
        offA0[fm] = r * 256 + ((q ^ (r & 15)) * 16);
    }
    int offB0;
    {
        int cl = wd * 16 + lr16;
        offB0 = 32768 + cl * 128 + ((q ^ (cl & 7)) * 16);
    }

    f32x4 acc[5][4];
#pragma unroll
    for (int g = 0; g < 5; ++g)
#pragma unroll
        for (int a = 0; a < 4; ++a)
            acc[g][a] = (f32x4){0.f, 0.f, 0.f, 0.f};

    STAGE_Y(0, 0);
    int cur = 0;
    for (int kt = 0; kt < 12; ++kt) {
        if (kt + 1 < 12) {
            STAGE_Y(cur ^ 1, (kt + 1) * 128);
            asm volatile("s_waitcnt vmcnt(13)" ::: "memory");
        } else {
            asm volatile("s_waitcnt vmcnt(0)" ::: "memory");
        }
        __builtin_amdgcn_s_barrier();
        __builtin_amdgcn_sched_barrier(0);
        const char* bb = smem + cur * BUFY;
        __builtin_amdgcn_s_setprio(1);
#pragma unroll
        for (int ks = 0; ks < 2; ++ks) {
            const int oX = ks * 64;
            half8 b0 = *(const half8*)(bb + (offB0 ^ oX));
            half8 b1 = *(const half8*)(bb + ((offB0 ^ oX) + 4096));
            half8 b2 = *(const half8*)(bb + ((offB0 ^ oX) + 8192));
            half8 b3 = *(const half8*)(bb + ((offB0 ^ oX) + 12288));  // Wfp
            half8 b4 = *(const half8*)(bb + ((offB0 ^ oX) + 16384));  // Wfh
#pragma unroll
            for (int fm = 0; fm < 4; ++fm) {
                half8 hl = *(const half8*)(bb + (offA0[fm] ^ oX));
                half8 hr = *(const half8*)(bb + ((offA0[fm] ^ oX) ^ 128));
                acc[3][fm] = __builtin_amdgcn_mfma_f32_16x16x32_f16(hl, b3, acc[3][fm], 0, 0, 0);
                acc[4][fm] = __builtin_amdgcn_mfma_f32_16x16x32_f16(hl, b4, acc[4][fm], 0, 0, 0);
                half8 hs = hl + hr;
                acc[0][fm] = __builtin_amdgcn_mfma_f32_16x16x32_f16(hs, b0, acc[0][fm], 0, 0, 0);
                acc[1][fm] = __builtin_amdgcn_mfma_f32_16x16x32_f16(hs, b1, acc[1][fm], 0, 0, 0);
                acc[2][fm] = __builtin_amdgcn_mfma_f32_16x16x32_f16(hs, b2, acc[2][fm], 0, 0, 0);
                acc[3][fm] = __builtin_amdgcn_mfma_f32_16x16x32_f16(hr, b4, acc[3][fm], 0, 0, 0);
                acc[4][fm] = __builtin_amdgcn_mfma_f32_16x16x32_f16(hr, b3, acc[4][fm], 0, 0, 0);
            }
        }
        __builtin_amdgcn_s_setprio(0);
        if (kt + 1 < 12) __builtin_amdgcn_s_barrier();
        cur ^= 1;
    }

    const int col = d0 + wd * 16 + lr16;
    const float bi = biou[col];
    const float bo = biou[768 + col];
    const float bu = biou[1536 + col];
    const float bf = bfv[col];
#pragma unroll
    for (int fm = 0; fm < 4; ++fm) {
        const int rb = mBase + wm * 64 + fm * 16 + q * 4;
#pragma unroll
        for (int r4 = 0; r4 < 4; ++r4) {
            int row = rb + r4;
            if (row < M) {
                float iv = acc[0][fm][r4] + bi;
                float ov = acc[1][fm][r4] + bo;
                float uv = acc[2][fm][r4] + bu;
                float fl = sigm(acc[3][fm][r4] + bf);
                float fr = sigm(acc[4][fm][r4] + bf);
                float clv = Cc[(size_t)(2 * row) * 768 + col];
                float crv = Cc[(size_t)(2 * row + 1) * 768 + col];
                float c = sigm(iv) * tanhfast(uv) + fl * clv + fr * crv;
                float h = sigm(ov) * tanhfast(c);
                if (finalLevel) {
                    out[row * 768 + col] = h;
                    out[6144 + row * 768 + col] = c;
                } else {
                    Hn[(size_t)row * 768 + col] = (_Float16)h;
                    Cn[(size_t)row * 768 + col] = c;
                }
            }
        }
    }
}

extern "C" void kernel_launch(void* const* d_in, const int* in_sizes, int n_in,
                              void* d_out, int out_size, void* d_ws, size_t ws_size,
                              hipStream_t stream)
{
    const float* leaf = (const float*)d_in[0];
    const float* Wiou = (const float*)d_in[1];
    const float* biou = (const float*)d_in[2];
    const float* Uiou = (const float*)d_in[3];
    const float* Wf   = (const float*)d_in[4];
    const float* bfv  = (const float*)d_in[5];
    const float* Uf   = (const float*)d_in[6];

    char* ws = (char*)d_ws;
    _Float16* Bw = (_Float16*)(ws);                  // 5x768x768 fp16 = 5,898,240 B
    _Float16* H0 = (_Float16*)(ws + 5898240);        // 65536x768 fp16
    _Float16* H1 = (_Float16*)(ws + 106561536);      // 32768x768 fp16
    float*    C0 = (float*)(ws + 156893184);         // 32768x768 f32
    float*    C1 = (float*)(ws + 257556480);         // 16384x768 f32

    prep_weights<<<1024, 256, 0, stream>>>(Wiou, Uiou, Wf, Uf, Bw);
    cast_leaves<<<2048, 256, 0, stream>>>(leaf, H0, 50331648 / 8);

    float* out = (float*)d_out;  // [2,8,768]
    _Float16* Hc = H0; _Float16* Hn = H1;
    float* Cc = C1; float* Cn = C0;
    int rows = 65536, level = 0;
    while (rows > 8) {
        int M = rows >> 1;
        if (M >= 4096) {
            int mblocks = M / 128;
            tree_level<<<mblocks * 12, 256, 0, stream>>>(Hc, Cc, Bw, biou, bfv,
                Hn, Cn, M, mblocks, level == 0 ? 1 : 0);
        } else if (M == 2048) {
            tree_small<<<16 * 24, 256, 0, stream>>>(Hc, Cc, Bw, biou, bfv,
                Hn, Cn, M);
        } else {
            int mblocks = (M + 127) / 128;
            int fin = (M == 8) ? 1 : 0;
            tree_tiny<<<mblocks * 24, 256, 0, stream>>>(Hc, Cc, Bw, biou, bfv,
                Hn, Cn, out, M, fin);
        }
        _Float16* th = Hc; Hc = Hn; Hn = th;
        float* tc = Cc; Cc = Cn; Cn = tc;
        rows = M; ++level;
    }
}

// Round 16
// 929.203 us; speedup vs baseline: 1.0069x; 1.0069x over previous
//
#include <hip/hip_runtime.h>

// Child-Sum Tree-LSTM, level-synchronous, B=8 L=8192 D=768.
// Per level: 5 fused K=768 GEMM products + LSTM cell epilogue.
//   acc0..2 (i,o,u) = hs @ (0.5*W_iou + U_iou)^T
//   acc3 (fl-pre)   = hl@Wfp^T + hr@Wfh^T,  Wfp = 0.5*W_f + U_f, Wfh = 0.5*W_f
//   acc4 (fr-pre)   = hl@Wfh^T + hr@Wfp^T
// R16 = revert to R14 (measured session best, 927us).
//  Big levels (M>=4096): kernel A — 128x64 tile, 4 waves, B in LDS,
//    2 blocks/CU, 2-deep gload_lds pipeline, counted vmcnt(9), setprio,
//    mb-major bijective XCD order.            [measured: 357us @ level 0]
//  Tail levels (M=2048..8): tree_small — 128x32 tile, 3 blocks/CU, vmcnt(7).
// Measured dead ends (all counter-verified): 3-deep pipeline (R3), stage
// reorder (R5), 2-phase split (R6), 3-block TLP at big M (R7), A-direct-reg
// (R8), 4-phase m201-lite (R9), cooperative tail (R10), 6-group algebra
// (R11), persistent-barrier tail (R12), B-direct-reg (R13), tail BK=64 (R15).

typedef _Float16 half8 __attribute__((ext_vector_type(8)));
typedef float f32x4 __attribute__((ext_vector_type(4)));

#define ROWB 1536        // bytes per 768-elem fp16 row
#define NT 24            // 768 / 32
#define BUFA 36864       // kernel A buffer: A 16384 + B 20480
#define BUFT 26624       // tail buffer: A 16384 + B 10240

__device__ __forceinline__ float sigm(float x){ return 1.f/(1.f+__expf(-x)); }
__device__ __forceinline__ float tanhfast(float x){ return 1.f - 2.f/(1.f+__expf(2.f*x)); }

__device__ __forceinline__ void gload16(const void* g, void* l){
  __builtin_amdgcn_global_load_lds((const __attribute__((address_space(1))) void*)g,
                                   (__attribute__((address_space(3))) void*)l, 16, 0, 0);
}

// Bw: 5 mats of 768x768 fp16: [0..2]=0.5*W_iou+U_iou (i,o,u), [3]=Wfp=0.5Wf+Uf, [4]=Wfh=0.5Wf
__global__ void prep_weights(const float* __restrict__ Wiou, const float* __restrict__ Uiou,
                             const float* __restrict__ Wf, const float* __restrict__ Uf,
                             _Float16* __restrict__ Bw)
{
    const int n1 = 2304 * 768, n2 = n1 + 589824, n3 = n2 + 589824;
    int stride = gridDim.x * blockDim.x;
    for (int idx = blockIdx.x * blockDim.x + threadIdx.x; idx < n3; idx += stride) {
        float v;
        if (idx < n1)      v = __fmaf_rn(0.5f, Wiou[idx], Uiou[idx]);
        else if (idx < n2) { int k = idx - n1; v = __fmaf_rn(0.5f, Wf[k], Uf[k]); }
        else               { int k = idx - n2; v = 0.5f * Wf[k]; }
        Bw[idx] = (_Float16)v;
    }
}

__global__ void cast_leaves(const float* __restrict__ x, _Float16* __restrict__ h, int n8)
{
    int stride = gridDim.x * blockDim.x;
    for (int i = blockIdx.x * blockDim.x + threadIdx.x; i < n8; i += stride) {
        float4 v0 = ((const float4*)x)[2 * i];
        float4 v1 = ((const float4*)x)[2 * i + 1];
        half8 o = { (_Float16)v0.x, (_Float16)v0.y, (_Float16)v0.z, (_Float16)v0.w,
                    (_Float16)v1.x, (_Float16)v1.y, (_Float16)v1.z, (_Float16)v1.w };
        ((half8*)h)[i] = o;
    }
}

// ================= kernel A: big levels (M>=4096) =================
// LDS per buffer: A 128 rows x 128B (row r chunk j: jj=j^(r&7), side=jj>>2,
// kchunk=jj&3 of H row 2*(mBase+r)+side); B at +16384: 5 mats x 32 pairs x
// 128B (pair p chunk j: jj=j^(p&7), col=d0+2p+(jj>>2), kchunk=jj&3).
__global__ __launch_bounds__(256, 2) void tree_level(
    const _Float16* __restrict__ Hc, const float* __restrict__ Cc,
    const _Float16* __restrict__ Bw,
    const float* __restrict__ biou, const float* __restrict__ bfv,
    _Float16* __restrict__ Hn, float* __restrict__ Cn,
    int M, int mblocks, int firstLevel)
{
    __shared__ __align__(16) char smem[2 * BUFA];
    const int tid = threadIdx.x;
    const int lane = tid & 63;
    const int w = tid >> 6;        // 0..3
    const int wm = w >> 1;         // 0..1 row-wave (64 rows)
    const int wd = w & 1;          // 0..1 col-wave (32 cols)

    // bijective XCD chunking; mb-major within XCD (H tile L2/L3-served)
    const int nwg = mblocks * 12;
    const int orig = blockIdx.x;
    const int xcd = orig & 7, qx = nwg >> 3, rx = nwg & 7;
    const int v = (xcd < rx ? xcd * (qx + 1) : rx * (qx + 1) + (xcd - rx) * qx) + (orig >> 3);
    const int mb = v / 12;
    const int d0c = v - mb * 12;
    const int mBase = mb * 128;
    const int d0 = d0c * 64;

    // stage sources: 4 A + 5 B per thread
    const int l3 = lane >> 3, j = lane & 7;
    const int jjA = j ^ l3;
    const int rbase = w * 8 + l3;
    unsigned offH[4];
#pragma unroll
    for (int s = 0; s < 4; ++s) {
        int gr = mBase + s * 32 + rbase;
        if (gr >= M) gr = M - 1;
        offH[s] = (unsigned)(2 * gr + (jjA >> 2)) * ROWB + (jjA & 3) * 16;
    }
    const int pB = w * 8 + l3;
    unsigned offWb[5];
#pragma unroll
    for (int t = 0; t < 5; ++t)
        offWb[t] = (unsigned)(t * 768 + d0 + 2 * pB + (jjA >> 2)) * ROWB + (jjA & 3) * 16;
    const int wK = w * 1024;

#define STAGE_A(bi, ko) do { \
    _Pragma("unroll") for (int s = 0; s < 4; ++s) \
        gload16((const char*)Hc + offH[s] + (ko), smem + (bi) * BUFA + s * 4096 + wK); \
    _Pragma("unroll") for (int t = 0; t < 5; ++t) \
        gload16((const char*)Bw + offWb[t] + (ko), smem + (bi) * BUFA + 16384 + t * 4096 + wK); \
} while (0)

    // compute offsets (kt-invariant)
    const int q = lane >> 4;
    const int lr16 = lane & 15;
    int offA[4], offB[2];
#pragma unroll
    for (int fm = 0; fm < 4; ++fm) {
        int r = wm * 64 + fm * 16 + lr16;
        offA[fm] = r * 128 + ((q ^ (r & 7)) * 16);
    }
#pragma unroll
    for (int fd = 0; fd < 2; ++fd) {
        int cl = wd * 32 + fd * 16 + lr16;
        int p = cl >> 1;
        int jb = ((cl & 1) * 4 + q) ^ (p & 7);
        offB[fd] = 16384 + p * 128 + jb * 16;
    }

    f32x4 acc[5][4][2];
#pragma unroll
    for (int g = 0; g < 5; ++g)
#pragma unroll
        for (int a = 0; a < 4; ++a)
#pragma unroll
            for (int b2 = 0; b2 < 2; ++b2)
                acc[g][a][b2] = (f32x4){0.f, 0.f, 0.f, 0.f};

    STAGE_A(0, 0);
    int cur = 0;
    for (int kt = 0; kt < NT; ++kt) {
        if (kt + 1 < NT) {
            STAGE_A(cur ^ 1, (kt + 1) * 64);
            asm volatile("s_waitcnt vmcnt(9)" ::: "memory");
        } else {
            asm volatile("s_waitcnt vmcnt(0)" ::: "memory");
        }
        __builtin_amdgcn_s_barrier();
        __builtin_amdgcn_sched_barrier(0);
        const char* bb = smem + cur * BUFA;
        half8 hl[4], hr[4];
#pragma unroll
        for (int fm = 0; fm < 4; ++fm) {
            hl[fm] = *(const half8*)(bb + offA[fm]);
            hr[fm] = *(const half8*)(bb + (offA[fm] ^ 64));
        }
        __builtin_amdgcn_s_setprio(1);
#pragma unroll
        for (int fd = 0; fd < 2; ++fd) {
            const char* bp = bb + offB[fd];
            half8 b0 = *(const half8*)(bp);
            half8 b1 = *(const half8*)(bp + 4096);
            half8 b2 = *(const half8*)(bp + 8192);
            half8 b3 = *(const half8*)(bp + 12288);   // Wfp
            half8 b4 = *(const half8*)(bp + 16384);   // Wfh
#pragma unroll
            for (int fm = 0; fm < 4; ++fm) {
                half8 hs = hl[fm] + hr[fm];
                acc[0][fm][fd] = __builtin_amdgcn_mfma_f32_16x16x32_f16(hs, b0, acc[0][fm][fd], 0, 0, 0);
                acc[1][fm][fd] = __builtin_amdgcn_mfma_f32_16x16x32_f16(hs, b1, acc[1][fm][fd], 0, 0, 0);
                acc[2][fm][fd] = __builtin_amdgcn_mfma_f32_16x16x32_f16(hs, b2, acc[2][fm][fd], 0, 0, 0);
                acc[3][fm][fd] = __builtin_amdgcn_mfma_f32_16x16x32_f16(hl[fm], b3, acc[3][fm][fd], 0, 0, 0);
                acc[3][fm][fd] = __builtin_amdgcn_mfma_f32_16x16x32_f16(hr[fm], b4, acc[3][fm][fd], 0, 0, 0);
                acc[4][fm][fd] = __builtin_amdgcn_mfma_f32_16x16x32_f16(hl[fm], b4, acc[4][fm][fd], 0, 0, 0);
                acc[4][fm][fd] = __builtin_amdgcn_mfma_f32_16x16x32_f16(hr[fm], b3, acc[4][fm][fd], 0, 0, 0);
            }
        }
        __builtin_amdgcn_s_setprio(0);
        if (kt + 1 < NT) __builtin_amdgcn_s_barrier();
        cur ^= 1;
    }

#pragma unroll
    for (int fd = 0; fd < 2; ++fd) {
        const int col = d0 + wd * 32 + fd * 16 + lr16;
        const float bi = biou[col];
        const float bo = biou[768 + col];
        const float bu = biou[1536 + col];
        const float bf = bfv[col];
#pragma unroll
        for (int fm = 0; fm < 4; ++fm) {
            const int rb = mBase + wm * 64 + fm * 16 + q * 4;
#pragma unroll
            for (int r4 = 0; r4 < 4; ++r4) {
                int row = rb + r4;
                if (row < M) {
                    float iv = acc[0][fm][fd][r4] + bi;
                    float ov = acc[1][fm][fd][r4] + bo;
                    float uv = acc[2][fm][fd][r4] + bu;
                    float fl = sigm(acc[3][fm][fd][r4] + bf);
                    float fr = sigm(acc[4][fm][fd][r4] + bf);
                    float clv = 0.f, crv = 0.f;
                    if (!firstLevel) {
                        clv = Cc[(size_t)(2 * row) * 768 + col];
                        crv = Cc[(size_t)(2 * row + 1) * 768 + col];
                    }
                    float c = sigm(iv) * tanhfast(uv) + fl * clv + fr * crv;
                    float h = sigm(ov) * tanhfast(c);
                    Hn[(size_t)row * 768 + col] = (_Float16)h;
                    Cn[(size_t)row * 768 + col] = c;
                }
            }
        }
    }
}

// ================= tree_small: tail levels (M=2048..8) =================
__global__ __launch_bounds__(256, 3) void tree_small(
    const _Float16* __restrict__ Hc, const float* __restrict__ Cc,
    const _Float16* __restrict__ Bw,
    const float* __restrict__ biou, const float* __restrict__ bfv,
    _Float16* __restrict__ Hn, float* __restrict__ Cn,
    float* __restrict__ out,
    int M, int finalLevel)
{
    __shared__ __align__(16) char smem[2 * BUFT];
    const int tid = threadIdx.x;
    const int lane = tid & 63;
    const int w = tid >> 6;
    const int wm = w >> 1;
    const int wd = w & 1;
    const int bid = blockIdx.x;
    const int mb = bid / 24;
    const int d0c = bid - mb * 24;
    const int mBase = mb * 128;
    const int d0 = d0c * 32;

    const int l3 = lane >> 3, j = lane & 7;
    const int jj0 = j ^ l3;

    // A stage sources (4 slots), clamped; B sources (3 slots, dup trick)
    unsigned offHa[4];
    int dstA[4];
#pragma unroll
    for (int s = 0; s < 4; ++s) {
        int u = s * 4 + w;
        int gr = mBase + u * 8 + l3;
        if (gr >= M) gr = M - 1;
        offHa[s] = (unsigned)(2 * gr + (jj0 >> 2)) * ROWB + (jj0 & 3) * 16;
        dstA[s] = u * 1024;
    }
    unsigned offWb[3];
    int dstB[3];
#pragma unroll
    for (int s = 0; s < 3; ++s) {
        int i = s * 4 + w;
        if (i >= 10) i -= 2;
        int t = i >> 1, half = i & 1;
        int p = half * 8 + l3;
        offWb[s] = (unsigned)(t * 768 + d0 + 2 * p + (jj0 >> 2)) * ROWB + (jj0 & 3) * 16;
        dstB[s] = 16384 + t * 2048 + half * 1024;
    }

#define STAGE_T(bi_, ko) do { \
    _Pragma("unroll") for (int s = 0; s < 4; ++s) \
        gload16((const char*)Hc + offHa[s] + (ko), smem + (bi_) * BUFT + dstA[s]); \
    _Pragma("unroll") for (int s = 0; s < 3; ++s) \
        gload16((const char*)Bw + offWb[s] + (ko), smem + (bi_) * BUFT + dstB[s]); \
} while (0)

    const int q = lane >> 4;
    const int lr16 = lane & 15;
    int offA[4];
#pragma unroll
    for (int fm = 0; fm < 4; ++fm) {
        int r = wm * 64 + fm * 16 + lr16;
        offA[fm] = r * 128 + ((q ^ (r & 7)) * 16);
    }
    int offB;
    {
        int cl = wd * 16 + lr16;
        int p = cl >> 1;
        int jb = ((cl & 1) * 4 + q) ^ (p & 7);
        offB = 16384 + p * 128 + jb * 16;
    }

    f32x4 acc[5][4];
#pragma unroll
    for (int g = 0; g < 5; ++g)
#pragma unroll
        for (int a = 0; a < 4; ++a)
            acc[g][a] = (f32x4){0.f, 0.f, 0.f, 0.f};

    STAGE_T(0, 0);
    int cur = 0;
    for (int kt = 0; kt < NT; ++kt) {
        if (kt + 1 < NT) {
            STAGE_T(cur ^ 1, (kt + 1) * 64);
            asm volatile("s_waitcnt vmcnt(7)" ::: "memory");
        } else {
            asm volatile("s_waitcnt vmcnt(0)" ::: "memory");
        }
        __builtin_amdgcn_s_barrier();
        __builtin_amdgcn_sched_barrier(0);
        const char* bb = smem + cur * BUFT;
        half8 b0 = *(const half8*)(bb + offB);
        half8 b1 = *(const half8*)(bb + offB + 2048);
        half8 b2 = *(const half8*)(bb + offB + 4096);
        half8 b3 = *(const half8*)(bb + offB + 6144);   // Wfp
        half8 b4 = *(const half8*)(bb + offB + 8192);   // Wfh
        __builtin_amdgcn_s_setprio(1);
#pragma unroll
        for (int fm = 0; fm < 4; ++fm) {
            half8 hl = *(const half8*)(bb + offA[fm]);
            half8 hr = *(const half8*)(bb + (offA[fm] ^ 64));
            acc[3][fm] = __builtin_amdgcn_mfma_f32_16x16x32_f16(hl, b3, acc[3][fm], 0, 0, 0);
            acc[4][fm] = __builtin_amdgcn_mfma_f32_16x16x32_f16(hl, b4, acc[4][fm], 0, 0, 0);
            half8 hs = hl + hr;
            acc[0][fm] = __builtin_amdgcn_mfma_f32_16x16x32_f16(hs, b0, acc[0][fm], 0, 0, 0);
            acc[1][fm] = __builtin_amdgcn_mfma_f32_16x16x32_f16(hs, b1, acc[1][fm], 0, 0, 0);
            acc[2][fm] = __builtin_amdgcn_mfma_f32_16x16x32_f16(hs, b2, acc[2][fm], 0, 0, 0);
            acc[3][fm] = __builtin_amdgcn_mfma_f32_16x16x32_f16(hr, b4, acc[3][fm], 0, 0, 0);
            acc[4][fm] = __builtin_amdgcn_mfma_f32_16x16x32_f16(hr, b3, acc[4][fm], 0, 0, 0);
        }
        __builtin_amdgcn_s_setprio(0);
        if (kt + 1 < NT) __builtin_amdgcn_s_barrier();
        cur ^= 1;
    }

    const int col = d0 + wd * 16 + lr16;
    const float bi = biou[col];
    const float bo = biou[768 + col];
    const float bu = biou[1536 + col];
    const float bf = bfv[col];
#pragma unroll
    for (int fm = 0; fm < 4; ++fm) {
        const int rb = mBase + wm * 64 + fm * 16 + q * 4;
#pragma unroll
        for (int r4 = 0; r4 < 4; ++r4) {
            int row = rb + r4;
            if (row < M) {
                float iv = acc[0][fm][r4] + bi;
                float ov = acc[1][fm][r4] + bo;
                float uv = acc[2][fm][r4] + bu;
                float fl = sigm(acc[3][fm][r4] + bf);
                float fr = sigm(acc[4][fm][r4] + bf);
                float clv = Cc[(size_t)(2 * row) * 768 + col];
                float crv = Cc[(size_t)(2 * row + 1) * 768 + col];
                float c = sigm(iv) * tanhfast(uv) + fl * clv + fr * crv;
                float h = sigm(ov) * tanhfast(c);
                if (finalLevel) {
                    out[row * 768 + col] = h;
                    out[6144 + row * 768 + col] = c;
                } else {
                    Hn[(size_t)row * 768 + col] = (_Float16)h;
                    Cn[(size_t)row * 768 + col] = c;
                }
            }
        }
    }
}

extern "C" void kernel_launch(void* const* d_in, const int* in_sizes, int n_in,
                              void* d_out, int out_size, void* d_ws, size_t ws_size,
                              hipStream_t stream)
{
    const float* leaf = (const float*)d_in[0];
    const float* Wiou = (const float*)d_in[1];
    const float* biou = (const float*)d_in[2];
    const float* Uiou = (const float*)d_in[3];
    const float* Wf   = (const float*)d_in[4];
    const float* bfv  = (const float*)d_in[5];
    const float* Uf   = (const float*)d_in[6];

    char* ws = (char*)d_ws;
    _Float16* Bw = (_Float16*)(ws);                  // 5x768x768 fp16 = 5,898,240 B
    _Float16* H0 = (_Float16*)(ws + 5898240);        // 65536x768 fp16
    _Float16* H1 = (_Float16*)(ws + 106561536);      // 32768x768 fp16
    float*    C0 = (float*)(ws + 156893184);         // 32768x768 f32
    float*    C1 = (float*)(ws + 257556480);         // 16384x768 f32

    prep_weights<<<1024, 256, 0, stream>>>(Wiou, Uiou, Wf, Uf, Bw);
    cast_leaves<<<2048, 256, 0, stream>>>(leaf, H0, 50331648 / 8);

    float* out = (float*)d_out;  // [2,8,768]
    _Float16* Hc = H0; _Float16* Hn = H1;
    float* Cc = C1; float* Cn = C0;
    int rows = 65536, level = 0;
    while (rows > 8) {
        int M = rows >> 1;
        if (M >= 4096) {
            int mblocks = M / 128;
            tree_level<<<mblocks * 12, 256, 0, stream>>>(Hc, Cc, Bw, biou, bfv,
                Hn, Cn, M, mblocks, level == 0 ? 1 : 0);
        } else {
            int mblocks = (M + 127) / 128;
            int fin = (M == 8) ? 1 : 0;
            tree_small<<<mblocks * 24, 256, 0, stream>>>(Hc, Cc, Bw, biou, bfv,
                Hn, Cn, out, M, fin);
        }
        _Float16* th = Hc; Hc = Hn; Hn = th;
        float* tc = Cc; Cc = Cn; Cn = tc;
        rows = M; ++level;
    }
}